// Round 9
// baseline (211.225 us; speedup 1.0000x reference)
//
#include <hip/hip_runtime.h>
#include <hip/hip_bf16.h>
#include <math.h>

// Problem constants (all fp32 on the wire)
#define B_   4
#define T_   2048
#define DM   1024      // d_model
#define DH   256       // d_hidden
#define M_   (B_*T_)   // 8192 rows

typedef __bf16 bf16;
typedef __attribute__((ext_vector_type(8))) __bf16 bf16x8;
typedef __attribute__((ext_vector_type(4))) float  f32x4;

__device__ inline float sigmoidf_(float x) { return 1.0f / (1.0f + __expf(-x)); }

// T2-style LDS XOR swizzle: rows are 64 bf16 = 8 chunks of 16B.
// chunk' = chunk ^ (row & 7). Involution; same formula on write & read.
__device__ inline int swz8(int r, int c) { return (((c >> 3) ^ (r & 7)) << 3); }

// ---- transpose+convert 4 weights -------------------------------------------
__global__ void transpose_cvt_all(const float* __restrict__ Wq, const float* __restrict__ Wk,
                                  const float* __restrict__ Wv, const float* __restrict__ Wo,
                                  bf16* __restrict__ Wq_t, bf16* __restrict__ Wk_t,
                                  bf16* __restrict__ Wv_t, bf16* __restrict__ Wo_t)
{
    const int bid = blockIdx.x;
    __shared__ float tile[32][33];
    const int w = bid >> 8, t = bid & 255;
    const float* in; bf16* out; int R, C, sh;
    if      (w == 0) { in = Wq; out = Wq_t; R = DM; C = DH; sh = 3; }
    else if (w == 1) { in = Wk; out = Wk_t; R = DM; C = DH; sh = 3; }
    else if (w == 2) { in = Wv; out = Wv_t; R = DM; C = DH; sh = 3; }
    else             { in = Wo; out = Wo_t; R = DH; C = DM; sh = 5; }
    const int r0 = (t >> sh) * 32, c0 = (t & ((1 << sh) - 1)) * 32;
    const int tx = threadIdx.x & 31, ty = threadIdx.x >> 5;
    #pragma unroll
    for (int i = ty; i < 32; i += 8)
        tile[i][tx] = in[(long)(r0 + i) * C + c0 + tx];
    __syncthreads();
    #pragma unroll
    for (int i = ty; i < 32; i += 8)
        out[(long)(c0 + i) * R + r0 + tx] = (bf16)tile[tx][i];
}

// r1-VERIFIED BK=64 inner loop at 64x64 tile: A staging unchanged; B staging
// is now the SAME verified pattern (one bf16x8, swz8). 8 waves = 2m x 4n,
// wave tile 32m x 16n, acc[2]. LDS 32 KB -> 4 blocks/CU (wave-cap = 100%).
#define GEMM_PHASE64(APTR, WT, ACC) {                                         \
    const float* aBase = &(APTR)[arowg * DM + ac8];                           \
    const bf16*  bBase = &(WT)[(long)(n0 + ar) * DM + ac8];                   \
    f32x4 pa0[2], pa1[2]; bf16x8 pb[2];                                       \
    _Pragma("unroll")                                                         \
    for (int p = 0; p < 2; ++p) {                                             \
        const float* ap = aBase + p * 64;                                     \
        pa0[p] = *(const f32x4*)ap; pa1[p] = *(const f32x4*)(ap + 4);         \
        pb[p]  = *(const bf16x8*)(bBase + p * 64);                            \
    }                                                                         \
    {   bf16x8 o;                                                             \
        _Pragma("unroll")                                                     \
        for (int e = 0; e < 4; ++e) { o[e] = (bf16)pa0[0][e]; o[4+e] = (bf16)pa1[0][e]; } \
        *(bf16x8*)&As[0][ar][swz8(ar, ac8)] = o;                              \
        *(bf16x8*)&Bs[0][ar][swz8(ar, ac8)] = pb[0];                          \
    }                                                                         \
    __syncthreads();                                                          \
    _Pragma("unroll")                                                         \
    for (int s = 0; s < 16; ++s) {                                            \
        const int cs = s & 1, ns = cs ^ 1;                                    \
        if (s + 2 < 16) {                                                     \
            const float* ap = aBase + (s + 2) * 64;                           \
            pa0[cs] = *(const f32x4*)ap; pa1[cs] = *(const f32x4*)(ap + 4);   \
            pb[cs]  = *(const bf16x8*)(bBase + (s + 2) * 64);                 \
        }                                                                     \
        if (s + 1 < 16) {                                                     \
            bf16x8 o;                                                         \
            _Pragma("unroll")                                                 \
            for (int e = 0; e < 4; ++e) { o[e] = (bf16)pa0[ns][e]; o[4+e] = (bf16)pa1[ns][e]; } \
            *(bf16x8*)&As[ns][ar][swz8(ar, ac8)] = o;                         \
            *(bf16x8*)&Bs[ns][ar][swz8(ar, ac8)] = pb[ns];                    \
        }                                                                     \
        _Pragma("unroll")                                                     \
        for (int kk = 0; kk < 64; kk += 32) {                                 \
            const int ra = wr * 32 + l16, rb = wc * 16 + l16;                 \
            bf16x8 a0 = *(const bf16x8*)&As[cs][ra     ][swz8(ra,      kk + q4 * 8)]; \
            bf16x8 a1 = *(const bf16x8*)&As[cs][ra + 16][swz8(ra + 16, kk + q4 * 8)]; \
            bf16x8 b0 = *(const bf16x8*)&Bs[cs][rb     ][swz8(rb,      kk + q4 * 8)]; \
            ACC[0] = __builtin_amdgcn_mfma_f32_16x16x32_bf16(a0, b0, ACC[0], 0, 0, 0); \
            ACC[1] = __builtin_amdgcn_mfma_f32_16x16x32_bf16(a1, b0, ACC[1], 0, 0, 0); \
        }                                                                     \
        __syncthreads();                                                      \
    } }

// ---- fused projections + in-block KV reduction -----------------------------
// z==0 (512 blocks, dispatched FIRST): KV plane. Tile rows = 4 batches x 16 j.
//   K-GEMM then V-GEMM (two phases), bounce to LDS bf16, reduce over batch
//   max / exp, write per-(jt,b,d) partials.
// z==1 (512 blocks): Yb = sigmoid(q@Wq).
__global__ __launch_bounds__(512, 8)
void proj_fused(const float* __restrict__ qin, const float* __restrict__ kin,
                const float* __restrict__ vin,
                const bf16* __restrict__ Wq_t, const bf16* __restrict__ Wk_t,
                const bf16* __restrict__ Wv_t,
                bf16* __restrict__ Yb, float* __restrict__ part_num,
                float* __restrict__ part_den)
{
    __shared__ __align__(16) char smem[32768];
    auto As = reinterpret_cast<bf16 (*)[64][64]>(smem);            // [2][64][64], 16 KB
    auto Bs = reinterpret_cast<bf16 (*)[64][64]>(smem + 16384);    // [2][64][64], 16 KB

    const int z   = blockIdx.z;
    const int bid = blockIdx.x;                   // 0..511
    const int tile = (bid & 7) * 64 + (bid >> 3); // XCD swizzle; n fastest in chunk
    const int n0 = (tile & 3) * 64;

    const int tid = threadIdx.x, lane = tid & 63, wave = tid >> 6;
    const int wr = wave >> 2, wc = wave & 3;      // wave: 32m x 16n
    const int q4 = lane >> 4, l16 = lane & 15;
    const int ar = tid >> 3, ac8 = (tid & 7) * 8; // staging: 64 rows x 64 cols

    const int m0 = (tile >> 2) * 64;              // z==1: row tile
    const int jt = tile >> 2;                     // z==0: j tile (16 j's)
    // z==0 row map: tile row = b*16 + jj  ->  global row b*T + jt*16 + jj
    const long arowg = (z == 1) ? (long)(m0 + ar)
                                : (long)(ar >> 4) * T_ + jt * 16 + (ar & 15);

    f32x4 accA[2] = {};    // Q (z==1) or K (z==0)
    f32x4 accV[2] = {};    // V (z==0)

    if (z == 1) {
        GEMM_PHASE64(qin, Wq_t, accA)
        // C/D: col = lane&15, row = (lane>>4)*4 + reg; sigmoid.
        #pragma unroll
        for (int i = 0; i < 2; ++i)
            #pragma unroll
            for (int r = 0; r < 4; ++r) {
                int gm = m0 + wr * 32 + i * 16 + q4 * 4 + r;
                int gn = n0 + wc * 16 + l16;
                Yb[(long)gm * DH + gn] = (bf16)sigmoidf_(accA[i][r]);
            }
    } else {
        GEMM_PHASE64(kin, Wk_t, accA)
        GEMM_PHASE64(vin, Wv_t, accV)
        // Bounce K,V tiles to LDS as bf16 (same precision as old Kb/Vb path).
        auto KL = reinterpret_cast<bf16 (*)[64]>(smem);            // [64][64], 8 KB
        auto VL = reinterpret_cast<bf16 (*)[64]>(smem + 8192);     // 8 KB
        float* red_n = (float*)(smem + 16384);                     // [4b][8grp][64d], 8 KB
        float* red_d = (float*)(smem + 24576);                     // 8 KB
        #pragma unroll
        for (int i = 0; i < 2; ++i)
            #pragma unroll
            for (int r = 0; r < 4; ++r) {
                const int row = wr * 32 + i * 16 + q4 * 4 + r;     // = b*16 + jj
                const int col = wc * 16 + l16;
                KL[row][col] = (bf16)accA[i][r];
                VL[row][col] = (bf16)accV[i][r];
            }
        __syncthreads();
        // thread -> (d = tid&63, grp = tid>>6); each grp covers 2 of 16 j's.
        const int d = tid & 63, grp = tid >> 6;
        float sn[B_] = {}, sd[B_] = {};
        #pragma unroll
        for (int jj2 = 0; jj2 < 2; ++jj2) {
            const int jj = grp * 2 + jj2;
            float k0 = (float)KL[jj][d],      k1 = (float)KL[16 + jj][d];
            float k2 = (float)KL[32 + jj][d], k3 = (float)KL[48 + jj][d];
            float mx = fmaxf(fmaxf(k0, k1), fmaxf(k2, k3));        // max over batch
            float e0 = __expf(k0 - mx), e1 = __expf(k1 - mx);
            float e2 = __expf(k2 - mx), e3 = __expf(k3 - mx);
            sn[0] += e0 * (float)VL[jj][d];      sd[0] += e0;
            sn[1] += e1 * (float)VL[16 + jj][d]; sd[1] += e1;
            sn[2] += e2 * (float)VL[32 + jj][d]; sd[2] += e2;
            sn[3] += e3 * (float)VL[48 + jj][d]; sd[3] += e3;
        }
        #pragma unroll
        for (int b = 0; b < B_; ++b) {
            red_n[(b * 8 + grp) * 64 + d] = sn[b];
            red_d[(b * 8 + grp) * 64 + d] = sd[b];
        }
        __syncthreads();
        if (tid < 256) {   // 4 b x 64 d: combine 8 groups, write partials
            const int b = tid >> 6, dd = tid & 63;
            float num = 0.f, den = 0.f;
            #pragma unroll
            for (int g = 0; g < 8; ++g) {
                num += red_n[(b * 8 + g) * 64 + dd];
                den += red_d[(b * 8 + g) * 64 + dd];
            }
            const int idx = ((jt * 4 + b) << 8) + n0 + dd;
            part_num[idx] = num;
            part_den[idx] = den;
        }
    }
}

// ---- merge partials -> rv = num/den ----------------------------------------
__global__ void merge_kv(const float* __restrict__ pn, const float* __restrict__ pd,
                         float* __restrict__ rv)
{
    const int t = blockIdx.x * 256 + threadIdx.x;   // 0..1023
    const int b = t >> 8, d = t & 255;
    float num = 0.f, den = 0.f;
    for (int jt = 0; jt < 128; ++jt) {
        num += pn[((jt * 4 + b) << 8) + d];
        den += pd[((jt * 4 + b) << 8) + d];
    }
    rv[t] = num / den;
}

// ---- output GEMM: out = (Yb * rv[b]) @ Wo, fp32 out ------------------------
// Same 64x64 occupancy-first geometry; rv folded into A staging. K=256.
__global__ __launch_bounds__(512, 8)
void gemm_out(const bf16* __restrict__ Yb, const bf16* __restrict__ Wo_t,
              const float* __restrict__ rv, float* __restrict__ out)
{
    __shared__ __align__(16) char smem[32768];
    auto As = reinterpret_cast<bf16 (*)[64][64]>(smem);
    auto Bs = reinterpret_cast<bf16 (*)[64][64]>(smem + 16384);
    __shared__ float rv_s[DH];

    // XCD swizzle (2048 % 8 == 0); n fastest within a chunk -> the 16 n-tiles
    // sharing a Yb m-panel stay on one XCD's L2.
    const int bid  = blockIdx.x;                   // 0..2047
    const int tile = (bid & 7) * 256 + (bid >> 3);
    const int m0 = (tile >> 4) * 64;
    const int n0 = (tile & 15) * 64;
    const int b  = m0 >> 11;                       // batch

    const int tid = threadIdx.x, lane = tid & 63, wave = tid >> 6;
    const int wr = wave >> 2, wc = wave & 3;
    const int q4 = lane >> 4, l16 = lane & 15;
    const int ar = tid >> 3, ac8 = (tid & 7) * 8;

    if (tid < DH) rv_s[tid] = rv[b * DH + tid];

    f32x4 acc[2] = {};

    const bf16* aBase = &Yb[(long)(m0 + ar) * DH + ac8];
    const bf16* bBase = &Wo_t[(long)(n0 + ar) * DH + ac8];

    bf16x8 pq[2], pb[2];
    #pragma unroll
    for (int p = 0; p < 2; ++p) {
        pq[p] = *(const bf16x8*)(aBase + p * 64);
        pb[p] = *(const bf16x8*)(bBase + p * 64);
    }
    __syncthreads();        // rv_s ready
    {   // stage slab 0 -> buf 0 (A scaled by rv)
        bf16x8 o;
        #pragma unroll
        for (int e = 0; e < 8; ++e)
            o[e] = (bf16)((float)pq[0][e] * rv_s[ac8 + e]);
        *(bf16x8*)&As[0][ar][swz8(ar, ac8)] = o;
        *(bf16x8*)&Bs[0][ar][swz8(ar, ac8)] = pb[0];
    }
    __syncthreads();

    #pragma unroll
    for (int s = 0; s < 4; ++s) {               // 4 slabs of BK=64
        const int cs = s & 1, ns = cs ^ 1;
        if (s + 2 < 4) {
            pq[cs] = *(const bf16x8*)(aBase + (s + 2) * 64);
            pb[cs] = *(const bf16x8*)(bBase + (s + 2) * 64);
        }
        if (s + 1 < 4) {
            bf16x8 o;
            #pragma unroll
            for (int e = 0; e < 8; ++e)
                o[e] = (bf16)((float)pq[ns][e] * rv_s[(s + 1) * 64 + ac8 + e]);
            *(bf16x8*)&As[ns][ar][swz8(ar, ac8)] = o;
            *(bf16x8*)&Bs[ns][ar][swz8(ar, ac8)] = pb[ns];
        }
        #pragma unroll
        for (int kk = 0; kk < 64; kk += 32) {
            const int ra = wr * 32 + l16, rb = wc * 16 + l16;
            bf16x8 a0 = *(const bf16x8*)&As[cs][ra     ][swz8(ra,      kk + q4 * 8)];
            bf16x8 a1 = *(const bf16x8*)&As[cs][ra + 16][swz8(ra + 16, kk + q4 * 8)];
            bf16x8 b0 = *(const bf16x8*)&Bs[cs][rb     ][swz8(rb,      kk + q4 * 8)];
            acc[0] = __builtin_amdgcn_mfma_f32_16x16x32_bf16(a0, b0, acc[0], 0, 0, 0);
            acc[1] = __builtin_amdgcn_mfma_f32_16x16x32_bf16(a1, b0, acc[1], 0, 0, 0);
        }
        __syncthreads();
    }
    #pragma unroll
    for (int i = 0; i < 2; ++i)
        #pragma unroll
        for (int r = 0; r < 4; ++r) {
            int gm = m0 + wr * 32 + i * 16 + q4 * 4 + r;
            int gn = n0 + wc * 16 + l16;
            out[(long)gm * DM + gn] = acc[i][r];
        }
}

// ---------------- launch ----------------
extern "C" void kernel_launch(void* const* d_in, const int* in_sizes, int n_in,
                              void* d_out, int out_size, void* d_ws, size_t ws_size,
                              hipStream_t stream)
{
    const float* q  = (const float*)d_in[0];
    const float* k  = (const float*)d_in[1];
    const float* v  = (const float*)d_in[2];
    const float* Wq = (const float*)d_in[3];
    const float* Wk = (const float*)d_in[4];
    const float* Wv = (const float*)d_in[5];
    const float* Wo = (const float*)d_in[6];
    // d_in[7] = W_bias: provably unused (exp_pos_bias == ones)
    float* out = (float*)d_out;

    // Workspace: ~7.05 MB
    char* ws = (char*)d_ws;
    bf16* Yb       = (bf16*)ws;  ws += (size_t)M_ * DH * sizeof(bf16);   // sigmoid(Q), 4 MB
    bf16* Wq_t     = (bf16*)ws;  ws += (size_t)DM * DH * sizeof(bf16);   // 0.5 MB
    bf16* Wk_t     = (bf16*)ws;  ws += (size_t)DM * DH * sizeof(bf16);
    bf16* Wv_t     = (bf16*)ws;  ws += (size_t)DM * DH * sizeof(bf16);
    bf16* Wo_t     = (bf16*)ws;  ws += (size_t)DM * DH * sizeof(bf16);
    float* rv      = (float*)ws; ws += (size_t)B_ * DH * sizeof(float);  // 4 KB
    float* part_n  = (float*)ws; ws += (size_t)128 * 4 * 256 * sizeof(float); // 512 KB
    float* part_d  = (float*)ws; ws += (size_t)128 * 4 * 256 * sizeof(float); // 512 KB

    transpose_cvt_all<<<1024, 256, 0, stream>>>(Wq, Wk, Wv, Wo,
                                                Wq_t, Wk_t, Wv_t, Wo_t);

    proj_fused<<<dim3(512, 1, 2), 512, 0, stream>>>(q, k, v, Wq_t, Wk_t, Wv_t,
                                                    Yb, part_n, part_d);
    merge_kv<<<4, 256, 0, stream>>>(part_n, part_d, rv);
    gemm_out<<<2048, 512, 0, stream>>>(Yb, Wo_t, rv, out);
}